// Round 1
// baseline (325.944 us; speedup 1.0000x reference)
//
#include <hip/hip_runtime.h>

// Problem dims
// B=64, S=63, F=64, T=12, NF=63, OUT=1, C=32, K=3, DILS=(1,2,4,8,16)
//
// Key structure: grouped convs => feature f's stack sees only feature f's series.
// Appended rows are [xf_i (features 0..62, known), out_i (feature 63)].
// => features 0..62 fully precomputable over the 74-long extended series;
//    only feature 63 has a 12-step sequential chain (1 new position/layer/step).
//
// Extended-series layer position ranges (features < 63):
//   in: t=0..73   (t<63 from x, t=63+j from x_forecasts[:, j], j=0..10)
//   L0 (d=1):  pos 0..71
//   L1 (d=2):  pos 0..67
//   L2 (d=4):  pos 0..59
//   L3 (d=8):  pos 0..43
//   L4 (d=16): pos 0..11   -> h4[b,f,i] (step-i conv feature)
// Feature 63 precompute (inputs t=0..62 only):
//   L0: 0..60, L1: 0..56, L2: 0..48, L3: 0..32, L4: 0
// Sequential step i (i=1..11) for feature 63:
//   L0 @60+i, L1 @56+i, L2 @48+i, L3 @32+i, L4 @i
// out_i[b] = pre[b,i] + linW[63]*h4_63[b,i]
//   pre[b,i] = sum_{f<63} linW[f]*h4[b,f,i] + sum_j linW[64+j]*xf[b,i,j] + linb

// ---------------- workspace layout (floats) ----------------
#define OFF_H4    0                        // [64][63][12] = 48384
#define OFF_ST    48384                    // feature-63 state, per-b stride 1760
#define ST_L0     0                        // L0 pos 57..60   (4*32)
#define ST_L1     128                      // L1 pos 49..56   (8*32)
#define ST_L2     384                      // L2 pos 33..48   (16*32)
#define ST_L3     896                      // L3 pos 1..27    (27*32)
#define ST_STRIDE 1760
#define OFF_H40   (48384 + 64*1760)        // [64] : h4 of feature 63 at step 0
// total = 161088 floats = 644 KB

// ---------------- kernel A: parallel precompute ----------------

__device__ __forceinline__ void mid_layer_A(
    const float* __restrict__ wrow,   // &wmid[m][(f*32+c)][0][0], 96 floats
    float bb,
    const float* __restrict__ bin,    // LDS in  [pos][32]
    float* __restrict__ bout,         // LDS out [pos][32]
    int P, int d, int c, int pg)
{
  float acc[9];
#pragma unroll
  for (int j = 0; j < 9; ++j) acc[j] = bb;

#pragma unroll
  for (int ci0 = 0; ci0 < 32; ci0 += 8) {
    float wreg[24];
#pragma unroll
    for (int q = 0; q < 6; ++q) {
      const float4 v = *reinterpret_cast<const float4*>(wrow + ci0 * 3 + q * 4);
      wreg[q*4+0] = v.x; wreg[q*4+1] = v.y; wreg[q*4+2] = v.z; wreg[q*4+3] = v.w;
    }
#pragma unroll
    for (int j = 0; j < 9; ++j) {
      const int p = pg + 8 * j;
      if (p < P) {
#pragma unroll
        for (int k = 0; k < 3; ++k) {
          const float* a = bin + (p + k * d) * 32 + ci0;
#pragma unroll
          for (int ci = 0; ci < 8; ++ci)
            acc[j] = fmaf(wreg[ci*3+k], a[ci], acc[j]);
        }
      }
    }
  }
#pragma unroll
  for (int j = 0; j < 9; ++j) {
    const int p = pg + 8 * j;
    if (p < P) bout[p*32+c] = fmaxf(acc[j], 0.f);
  }
}

__global__ __launch_bounds__(256) void tcn_pre(
    const float* __restrict__ x, const float* __restrict__ xfc,
    const float* __restrict__ w0, const float* __restrict__ b0,
    const float* __restrict__ wmid, const float* __restrict__ bmid,
    const float* __restrict__ wlast, const float* __restrict__ blast,
    float* __restrict__ ws)
{
  const int blk = blockIdx.x;
  const int b = blk >> 6;
  const int f = blk & 63;
  const bool lastf = (f == 63);
  const int tid = threadIdx.x;
  const int c = tid & 31, pg = tid >> 5;

  __shared__ float sIn[74];
  __shared__ float bufA[72 * 32];   // L0, later L2
  __shared__ float bufB[68 * 32];   // L1, later L3

  // ---- load input series ----
  const int INLEN = lastf ? 63 : 74;
  for (int t = tid; t < INLEN; t += 256)
    sIn[t] = (t < 63) ? x[(b * 63 + t) * 64 + f]
                      : xfc[(b * 12 + (t - 63)) * 63 + f];
  __syncthreads();

  // ---- L0 (d=1, 1->32 channels) ----
  const int P0 = lastf ? 61 : 72;
  {
    const float ww0 = w0[(f*32+c)*3+0];
    const float ww1 = w0[(f*32+c)*3+1];
    const float ww2 = w0[(f*32+c)*3+2];
    const float bb  = b0[f*32+c];
    for (int p = pg; p < P0; p += 8) {
      float v = fmaf(ww0, sIn[p], fmaf(ww1, sIn[p+1], fmaf(ww2, sIn[p+2], bb)));
      bufA[p*32+c] = fmaxf(v, 0.f);
    }
  }
  __syncthreads();

  float* st = ws + OFF_ST + b * ST_STRIDE;
  if (lastf) {  // store L0 pos 57..60 (reads bufA; bufA next overwritten after post-L1 barrier+L2)
    for (int t = tid; t < 4 * 32; t += 256) st[ST_L0 + t] = bufA[57 * 32 + t];
  }

  // ---- L1 (d=2) ----
  {
    const int P1 = lastf ? 57 : 68;
    const float* wrow = wmid + 0 * (2048 * 96) + (f*32+c) * 96;
    mid_layer_A(wrow, bmid[0 * 2048 + f*32+c], bufA, bufB, P1, 2, c, pg);
  }
  __syncthreads();
  if (lastf) {  // store L1 pos 49..56
    for (int t = tid; t < 8 * 32; t += 256) st[ST_L1 + t] = bufB[49 * 32 + t];
  }

  // ---- L2 (d=4) ----
  {
    const int P2 = lastf ? 49 : 60;
    const float* wrow = wmid + 1 * (2048 * 96) + (f*32+c) * 96;
    mid_layer_A(wrow, bmid[1 * 2048 + f*32+c], bufB, bufA, P2, 4, c, pg);
  }
  __syncthreads();
  if (lastf) {  // store L2 pos 33..48
    for (int t = tid; t < 16 * 32; t += 256) st[ST_L2 + t] = bufA[33 * 32 + t];
  }

  // ---- L3 (d=8) ----
  {
    const int P3 = lastf ? 33 : 44;
    const float* wrow = wmid + 2 * (2048 * 96) + (f*32+c) * 96;
    mid_layer_A(wrow, bmid[2 * 2048 + f*32+c], bufA, bufB, P3, 8, c, pg);
  }
  __syncthreads();
  if (lastf) {  // store L3 pos 1..27
    for (int t = tid; t < 27 * 32; t += 256) st[ST_L3 + t] = bufB[1 * 32 + t];
  }

  // ---- L4 (d=16, 32->1, no relu) ----
  const int P4 = lastf ? 1 : 12;
  if (tid < P4) {
    const int p = tid;
    float acc = blast[f];
#pragma unroll
    for (int k = 0; k < 3; ++k) {
      const float* a = bufB + (p + 16 * k) * 32;
#pragma unroll
      for (int ci = 0; ci < 32; ++ci)
        acc = fmaf(wlast[f * 96 + ci * 3 + k], a[ci], acc);
    }
    if (!lastf) ws[OFF_H4 + (b * 63 + f) * 12 + p] = acc;
    else        ws[OFF_H40 + b] = acc;
  }
}

// ---------------- kernel B: sequential feature-63 chain ----------------

__device__ __forceinline__ void seq_mid(
    const float* __restrict__ wmL,   // LDS [96][33]: [(ci*3+k)*33 + c]
    float bb,
    const float* __restrict__ AIN, int inBase,
    float* __restrict__ AOUT, int outBase,
    int q, int d, int c, int h)
{
  float acc = 0.f;
  const int cib = h * 16;
#pragma unroll
  for (int ci = 0; ci < 16; ++ci) {
#pragma unroll
    for (int k = 0; k < 3; ++k)
      acc = fmaf(wmL[((cib + ci) * 3 + k) * 33 + c],
                 AIN[(q + k * d - inBase) * 32 + (cib + ci)], acc);
  }
  acc += __shfl_down(acc, 32);
  if (h == 0) AOUT[(q - outBase) * 32 + c] = fmaxf(acc + bb, 0.f);
}

__global__ __launch_bounds__(64) void tcn_seq(
    const float* __restrict__ x, const float* __restrict__ xfc,
    const float* __restrict__ w0, const float* __restrict__ b0,
    const float* __restrict__ wmid, const float* __restrict__ bmid,
    const float* __restrict__ wlast, const float* __restrict__ blast,
    const float* __restrict__ linW, const float* __restrict__ linb,
    const float* __restrict__ ws, float* __restrict__ out)
{
  const int b = blockIdx.x;
  const int tid = threadIdx.x;
  const int c = tid & 31, h = tid >> 5;

  __shared__ float wm[3][96 * 33];  // transposed, padded: [(ci*3+k)*33 + co]
  __shared__ float wl[96];
  // offset-indexed activation windows for feature 63:
  __shared__ float L0s[15 * 32];    // pos 57..71
  __shared__ float L1s[19 * 32];    // pos 49..67
  __shared__ float L2s[27 * 32];    // pos 33..59
  __shared__ float L3s[43 * 32];    // pos 1..43
  __shared__ float in63[74];
  __shared__ float pre[12];

  // ---- stage feature-63 mid weights, transposed ----
  for (int m = 0; m < 3; ++m) {
    const float* src = wmid + m * (2048 * 96) + 2016 * 96;  // rows co=0..31, 96 each
    for (int o = tid * 4; o < 3072; o += 64 * 4) {
      const float4 v = *reinterpret_cast<const float4*>(src + o);
      const int co = o / 96, r = o % 96;   // 96%4==0 -> no row crossing
      wm[m][(r + 0) * 33 + co] = v.x;
      wm[m][(r + 1) * 33 + co] = v.y;
      wm[m][(r + 2) * 33 + co] = v.z;
      wm[m][(r + 3) * 33 + co] = v.w;
    }
  }
  for (int t = tid; t < 96; t += 64) wl[t] = wlast[63 * 96 + t];

  // ---- load precomputed feature-63 state ----
  {
    const float* st = ws + OFF_ST + b * ST_STRIDE;
    for (int t = tid; t < 4 * 32;  t += 64) L0s[t] = st[ST_L0 + t];
    for (int t = tid; t < 8 * 32;  t += 64) L1s[t] = st[ST_L1 + t];
    for (int t = tid; t < 16 * 32; t += 64) L2s[t] = st[ST_L2 + t];
    for (int t = tid; t < 27 * 32; t += 64) L3s[t] = st[ST_L3 + t];
  }
  for (int t = tid; t < 63; t += 64) in63[t] = x[(b * 63 + t) * 64 + 63];

  // ---- linear partials pre[b,i] (all terms except feature 63) ----
  const float lw  = (tid < 63) ? linW[tid] : 0.f;
  const float lwx = (tid < 63) ? linW[64 + tid] : 0.f;
  const float linb0 = linb[0];
  const float lw63  = linW[63];
  for (int i = 0; i < 12; ++i) {
    float v = 0.f;
    if (tid < 63)
      v = lw * ws[OFF_H4 + (b * 63 + tid) * 12 + i] + lwx * xfc[(b * 12 + i) * 63 + tid];
#pragma unroll
    for (int s = 32; s > 0; s >>= 1) v += __shfl_down(v, s);
    if (tid == 0) pre[i] = v + linb0;
  }

  // ---- per-lane feature-63 small weights ----
  const float w00 = w0[(2016 + c) * 3 + 0];
  const float w01 = w0[(2016 + c) * 3 + 1];
  const float w02 = w0[(2016 + c) * 3 + 2];
  const float b00 = b0[2016 + c];
  const float bm0 = bmid[0 * 2048 + 2016 + c];
  const float bm1 = bmid[1 * 2048 + 2016 + c];
  const float bm2 = bmid[2 * 2048 + 2016 + c];
  const float bl  = blast[63];
  __syncthreads();

  // ---- step 0 ----
  if (tid == 0) {
    const float o0 = pre[0] + lw63 * ws[OFF_H40 + b];
    out[b * 12 + 0] = o0;
    in63[63] = o0;
  }
  __syncthreads();

  // ---- steps 1..11 ----
  for (int i = 1; i < 12; ++i) {
    // L0 @ 60+i
    if (h == 0) {
      const int q0 = 60 + i;
      float v = fmaf(w00, in63[q0], fmaf(w01, in63[q0+1], fmaf(w02, in63[q0+2], b00)));
      L0s[(q0 - 57) * 32 + c] = fmaxf(v, 0.f);
    }
    __syncthreads();
    seq_mid(wm[0], bm0, L0s, 57, L1s, 49, 56 + i, 2, c, h);
    __syncthreads();
    seq_mid(wm[1], bm1, L1s, 49, L2s, 33, 48 + i, 4, c, h);
    __syncthreads();
    seq_mid(wm[2], bm2, L2s, 33, L3s, 1,  32 + i, 8, c, h);
    __syncthreads();
    // L4 @ i, then linear
    float acc = 0.f;
    if (tid < 32) {
#pragma unroll
      for (int k = 0; k < 3; ++k)
        acc = fmaf(wl[tid * 3 + k], L3s[(i + 16 * k - 1) * 32 + tid], acc);
    }
#pragma unroll
    for (int s = 16; s > 0; s >>= 1) acc += __shfl_down(acc, s);
    if (tid == 0) {
      const float h4v = acc + bl;
      const float oi = pre[i] + lw63 * h4v;
      out[b * 12 + i] = oi;
      if (i <= 10) in63[63 + i] = oi;
    }
    __syncthreads();
  }
}

// ---------------- launcher ----------------

extern "C" void kernel_launch(void* const* d_in, const int* in_sizes, int n_in,
                              void* d_out, int out_size, void* d_ws, size_t ws_size,
                              hipStream_t stream) {
  const float* x     = (const float*)d_in[0];
  const float* xfc   = (const float*)d_in[1];
  const float* w0    = (const float*)d_in[2];
  const float* b0    = (const float*)d_in[3];
  const float* wmid  = (const float*)d_in[4];
  const float* bmid  = (const float*)d_in[5];
  const float* wlast = (const float*)d_in[6];
  const float* blast = (const float*)d_in[7];
  const float* linW  = (const float*)d_in[8];
  const float* linb  = (const float*)d_in[9];
  float* out = (float*)d_out;
  float* ws  = (float*)d_ws;

  tcn_pre<<<64 * 64, 256, 0, stream>>>(x, xfc, w0, b0, wmid, bmid, wlast, blast, ws);
  tcn_seq<<<64, 64, 0, stream>>>(x, xfc, w0, b0, wmid, bmid, wlast, blast, linW, linb, ws, out);
}

// Round 2
// 172.191 us; speedup vs baseline: 1.8929x; 1.8929x over previous
//
#include <hip/hip_runtime.h>

// Problem dims: B=64, S=63, F=64, T=12, NF=63, OUT=1, C=32, K=3, DILS=(1,2,4,8,16)
//
// Grouped convs => feature f's stack sees only feature f's series. Appended
// window rows are [xf_i (features 0..62, known), out_i (feature 63)].
// => features 0..62 fully precomputable over the 74-long extended series;
//    only feature 63 has a 12-step sequential chain.
//
// tcn_pre thread mapping (this round): lanes = positions, wave = co-octet.
//  - activations in LDS as [ch][PPAD] -> per-lane consecutive ds_read_b32
//  - weights wave-uniform -> scalar s_loads (zero VGPR, no VMEM scatter)
// Uniform position ranges for ALL blocks: L0:72 L1:68 L2:60 L3:44 L4:12
// (f=63 zero-fills forecast tail; garbage regions never read, slices valid.)

#define PPAD 81

// ---------------- workspace layout (floats) ----------------
#define OFF_H4    0                        // [64][63][12] = 48384
#define OFF_ST    48384                    // feature-63 state, per-b stride 1760
#define ST_L0     0                        // L0 pos 57..60   (4*32)   [pos][ch]
#define ST_L1     128                      // L1 pos 49..56   (8*32)
#define ST_L2     384                      // L2 pos 33..48   (16*32)
#define ST_L3     896                      // L3 pos 1..27    (27*32)
#define ST_STRIDE 1760
#define OFF_H40   (48384 + 64*1760)        // [64] : h4 of feature 63 at step 0

// ---------------- kernel A: parallel precompute ----------------

__device__ __forceinline__ void mid_layer(
    const float* __restrict__ wb,    // scalar base: this wave's 8 co rows (96 floats each)
    const float* __restrict__ bbp,   // scalar base: 8 biases
    const float* __restrict__ bin,   // LDS in  [32][PPAD]
    float* __restrict__ bout,        // LDS out [32][PPAD]
    const int P, const int d, const int gco, const int lane, const bool two)
{
#pragma unroll
  for (int it = 0; it < 2; ++it) {
    if (it == 1 && !two) break;
    const int p = lane + it * 64;
    if (p < P) {
      float acc[8];
#pragma unroll
      for (int j = 0; j < 8; ++j) acc[j] = bbp[j];
#pragma unroll
      for (int ci0 = 0; ci0 < 32; ci0 += 8) {
        float a[8][3];
#pragma unroll
        for (int ci = 0; ci < 8; ++ci)
#pragma unroll
          for (int k = 0; k < 3; ++k)
            a[ci][k] = bin[(ci0 + ci) * PPAD + p + k * d];
#pragma unroll
        for (int j = 0; j < 8; ++j)
#pragma unroll
          for (int ci = 0; ci < 8; ++ci)
#pragma unroll
            for (int k = 0; k < 3; ++k)
              acc[j] = fmaf(wb[j * 96 + (ci0 + ci) * 3 + k], a[ci][k], acc[j]);
      }
#pragma unroll
      for (int j = 0; j < 8; ++j)
        bout[(gco + j) * PPAD + p] = fmaxf(acc[j], 0.f);
    }
  }
}

__global__ __launch_bounds__(256, 4) void tcn_pre(
    const float* __restrict__ x, const float* __restrict__ xfc,
    const float* __restrict__ w0, const float* __restrict__ b0,
    const float* __restrict__ wmid, const float* __restrict__ bmid,
    const float* __restrict__ wlast, const float* __restrict__ blast,
    float* __restrict__ ws)
{
  const int blk = blockIdx.x;
  const int b = blk >> 6;
  const int f = blk & 63;
  const bool lastf = (f == 63);
  const int tid = threadIdx.x;
  const int lane = tid & 63;
  const int g = __builtin_amdgcn_readfirstlane(tid >> 6);  // wave id = co-octet

  __shared__ float sIn[80];
  __shared__ float bufA[32 * PPAD];
  __shared__ float bufB[32 * PPAD];

  // ---- load input series (tail zero-filled; f=63 gets no forecast values) ----
  for (int t = tid; t < 80; t += 256) {
    float v = 0.f;
    if (t < 63)                 v = x[(b * 63 + t) * 64 + f];
    else if (t < 74 && !lastf)  v = xfc[(b * 12 + (t - 63)) * 63 + f];
    sIn[t] = v;
  }
  __syncthreads();

  // ---- L0 (d=1, 1->32ch), 72 positions ----
  {
    const float* wb  = w0 + (f * 32 + g * 8) * 3;
    const float* bbp = b0 + f * 32 + g * 8;
#pragma unroll
    for (int it = 0; it < 2; ++it) {
      const int p = lane + it * 64;
      if (p < 72) {
        const float i0 = sIn[p], i1 = sIn[p + 1], i2 = sIn[p + 2];
#pragma unroll
        for (int j = 0; j < 8; ++j) {
          float v = fmaf(wb[j * 3 + 0], i0,
                    fmaf(wb[j * 3 + 1], i1,
                    fmaf(wb[j * 3 + 2], i2, bbp[j])));
          bufA[(g * 8 + j) * PPAD + p] = fmaxf(v, 0.f);
        }
      }
    }
  }
  __syncthreads();

  float* st = ws + OFF_ST + b * ST_STRIDE;
  if (lastf) {  // L0 slice pos 57..60, layout [pos][ch] (bufA not written until L2)
    for (int t = tid; t < 128; t += 256)
      st[ST_L0 + t] = bufA[(t & 31) * PPAD + 57 + (t >> 5)];
  }

  // ---- L1 (d=2), 68 positions ----
  mid_layer(wmid + (f * 32 + g * 8) * 96, bmid + f * 32 + g * 8,
            bufA, bufB, 68, 2, g * 8, lane, true);
  __syncthreads();
  if (lastf) {  // L1 slice pos 49..56
    for (int t = tid; t < 256; t += 256)
      st[ST_L1 + t] = bufB[(t & 31) * PPAD + 49 + (t >> 5)];
  }

  // ---- L2 (d=4), 60 positions ----
  mid_layer(wmid + 196608 + (f * 32 + g * 8) * 96, bmid + 2048 + f * 32 + g * 8,
            bufB, bufA, 60, 4, g * 8, lane, false);
  __syncthreads();
  if (lastf) {  // L2 slice pos 33..48
    for (int t = tid; t < 512; t += 256)
      st[ST_L2 + t] = bufA[(t & 31) * PPAD + 33 + (t >> 5)];
  }

  // ---- L3 (d=8), 44 positions ----
  mid_layer(wmid + 2 * 196608 + (f * 32 + g * 8) * 96, bmid + 2 * 2048 + f * 32 + g * 8,
            bufA, bufB, 44, 8, g * 8, lane, false);
  __syncthreads();
  if (lastf) {  // L3 slice pos 1..27
    for (int t = tid; t < 864; t += 256)
      st[ST_L3 + t] = bufB[(t & 31) * PPAD + 1 + (t >> 5)];
  }

  // ---- L4 (d=16, 32->1, no relu), 12 positions ----
  if (tid < 12) {
    const int p = tid;
    float acc = blast[f];
    const float* wl = wlast + f * 96;
#pragma unroll
    for (int ci = 0; ci < 32; ++ci)
#pragma unroll
      for (int k = 0; k < 3; ++k)
        acc = fmaf(wl[ci * 3 + k], bufB[ci * PPAD + p + 16 * k], acc);
    if (!lastf)     ws[OFF_H4 + (b * 63 + f) * 12 + p] = acc;
    else if (p == 0) ws[OFF_H40 + b] = acc;
  }
}

// ---------------- kernel B: sequential feature-63 chain (unchanged) ----------------

__device__ __forceinline__ void seq_mid(
    const float* __restrict__ wmL,   // LDS [96][33]: [(ci*3+k)*33 + c]
    float bb,
    const float* __restrict__ AIN, int inBase,
    float* __restrict__ AOUT, int outBase,
    int q, int d, int c, int h)
{
  float acc = 0.f;
  const int cib = h * 16;
#pragma unroll
  for (int ci = 0; ci < 16; ++ci) {
#pragma unroll
    for (int k = 0; k < 3; ++k)
      acc = fmaf(wmL[((cib + ci) * 3 + k) * 33 + c],
                 AIN[(q + k * d - inBase) * 32 + (cib + ci)], acc);
  }
  acc += __shfl_down(acc, 32);
  if (h == 0) AOUT[(q - outBase) * 32 + c] = fmaxf(acc + bb, 0.f);
}

__global__ __launch_bounds__(64) void tcn_seq(
    const float* __restrict__ x, const float* __restrict__ xfc,
    const float* __restrict__ w0, const float* __restrict__ b0,
    const float* __restrict__ wmid, const float* __restrict__ bmid,
    const float* __restrict__ wlast, const float* __restrict__ blast,
    const float* __restrict__ linW, const float* __restrict__ linb,
    const float* __restrict__ ws, float* __restrict__ out)
{
  const int b = blockIdx.x;
  const int tid = threadIdx.x;
  const int c = tid & 31, h = tid >> 5;

  __shared__ float wm[3][96 * 33];  // transposed, padded: [(ci*3+k)*33 + co]
  __shared__ float wl[96];
  __shared__ float L0s[15 * 32];    // pos 57..71
  __shared__ float L1s[19 * 32];    // pos 49..67
  __shared__ float L2s[27 * 32];    // pos 33..59
  __shared__ float L3s[43 * 32];    // pos 1..43
  __shared__ float in63[74];
  __shared__ float pre[12];

  for (int m = 0; m < 3; ++m) {
    const float* src = wmid + m * (2048 * 96) + 2016 * 96;
    for (int o = tid * 4; o < 3072; o += 64 * 4) {
      const float4 v = *reinterpret_cast<const float4*>(src + o);
      const int co = o / 96, r = o % 96;
      wm[m][(r + 0) * 33 + co] = v.x;
      wm[m][(r + 1) * 33 + co] = v.y;
      wm[m][(r + 2) * 33 + co] = v.z;
      wm[m][(r + 3) * 33 + co] = v.w;
    }
  }
  for (int t = tid; t < 96; t += 64) wl[t] = wlast[63 * 96 + t];

  {
    const float* stp = ws + OFF_ST + b * ST_STRIDE;
    for (int t = tid; t < 4 * 32;  t += 64) L0s[t] = stp[ST_L0 + t];
    for (int t = tid; t < 8 * 32;  t += 64) L1s[t] = stp[ST_L1 + t];
    for (int t = tid; t < 16 * 32; t += 64) L2s[t] = stp[ST_L2 + t];
    for (int t = tid; t < 27 * 32; t += 64) L3s[t] = stp[ST_L3 + t];
  }
  for (int t = tid; t < 63; t += 64) in63[t] = x[(b * 63 + t) * 64 + 63];

  const float lw  = (tid < 63) ? linW[tid] : 0.f;
  const float lwx = (tid < 63) ? linW[64 + tid] : 0.f;
  const float linb0 = linb[0];
  const float lw63  = linW[63];
  for (int i = 0; i < 12; ++i) {
    float v = 0.f;
    if (tid < 63)
      v = lw * ws[OFF_H4 + (b * 63 + tid) * 12 + i] + lwx * xfc[(b * 12 + i) * 63 + tid];
#pragma unroll
    for (int s = 32; s > 0; s >>= 1) v += __shfl_down(v, s);
    if (tid == 0) pre[i] = v + linb0;
  }

  const float w00 = w0[(2016 + c) * 3 + 0];
  const float w01 = w0[(2016 + c) * 3 + 1];
  const float w02 = w0[(2016 + c) * 3 + 2];
  const float b00 = b0[2016 + c];
  const float bm0 = bmid[0 * 2048 + 2016 + c];
  const float bm1 = bmid[1 * 2048 + 2016 + c];
  const float bm2 = bmid[2 * 2048 + 2016 + c];
  const float bl  = blast[63];
  __syncthreads();

  if (tid == 0) {
    const float o0 = pre[0] + lw63 * ws[OFF_H40 + b];
    out[b * 12 + 0] = o0;
    in63[63] = o0;
  }
  __syncthreads();

  for (int i = 1; i < 12; ++i) {
    if (h == 0) {
      const int q0 = 60 + i;
      float v = fmaf(w00, in63[q0], fmaf(w01, in63[q0 + 1], fmaf(w02, in63[q0 + 2], b00)));
      L0s[(q0 - 57) * 32 + c] = fmaxf(v, 0.f);
    }
    __syncthreads();
    seq_mid(wm[0], bm0, L0s, 57, L1s, 49, 56 + i, 2, c, h);
    __syncthreads();
    seq_mid(wm[1], bm1, L1s, 49, L2s, 33, 48 + i, 4, c, h);
    __syncthreads();
    seq_mid(wm[2], bm2, L2s, 33, L3s, 1,  32 + i, 8, c, h);
    __syncthreads();
    float acc = 0.f;
    if (tid < 32) {
#pragma unroll
      for (int k = 0; k < 3; ++k)
        acc = fmaf(wl[tid * 3 + k], L3s[(i + 16 * k - 1) * 32 + tid], acc);
    }
#pragma unroll
    for (int s = 16; s > 0; s >>= 1) acc += __shfl_down(acc, s);
    if (tid == 0) {
      const float h4v = acc + bl;
      const float oi = pre[i] + lw63 * h4v;
      out[b * 12 + i] = oi;
      if (i <= 10) in63[63 + i] = oi;
    }
    __syncthreads();
  }
}

// ---------------- launcher ----------------

extern "C" void kernel_launch(void* const* d_in, const int* in_sizes, int n_in,
                              void* d_out, int out_size, void* d_ws, size_t ws_size,
                              hipStream_t stream) {
  const float* x     = (const float*)d_in[0];
  const float* xfc   = (const float*)d_in[1];
  const float* w0    = (const float*)d_in[2];
  const float* b0    = (const float*)d_in[3];
  const float* wmid  = (const float*)d_in[4];
  const float* bmid  = (const float*)d_in[5];
  const float* wlast = (const float*)d_in[6];
  const float* blast = (const float*)d_in[7];
  const float* linW  = (const float*)d_in[8];
  const float* linb  = (const float*)d_in[9];
  float* out = (float*)d_out;
  float* ws  = (float*)d_ws;

  tcn_pre<<<64 * 64, 256, 0, stream>>>(x, xfc, w0, b0, wmid, bmid, wlast, blast, ws);
  tcn_seq<<<64, 64, 0, stream>>>(x, xfc, w0, b0, wmid, bmid, wlast, blast, linW, linb, ws, out);
}

// Round 3
// 61.510 us; speedup vs baseline: 5.2990x; 2.7994x over previous
//
#include <hip/hip_runtime.h>

// B=64, S=63, F=64, T=12, NF=63, OUT=1, C=32, K=3, DILS=(1,2,4,8,16)
//
// tcn_pre this round: mid layers on MFMA (f16 in, f32 accum).
// Per (b,f) block: out[32co x P] = sum_{t,h} W[t,h][32x16] @ Act[16 x 32pos]
// via v_mfma_f32_32x32x16_f16; 6 MFMA per 32-pos tile per layer.
// Activations: LDS f16 [pos][36] (72B rows: 2-way bank = free, 8B aligned).
// Weights: repacked once per launch into fragment-ready global layout
//   wpk[m][f][t][h][lane][j] so each wave loads 6 x b128 coalesced.
// A-frag: row(co)=lane&31, k=(lane>>5)*8+j ; B-frag: col(pos)=lane&31, same k.
// C/D: col(pos)=lane&31, row(co)=(r&3)+8*(r>>2)+4*(lane>>5)  [HW-verified map].
// Full 32-col tiles compute garbage in out-of-range cols; buffers padded to
// 100 zero-initialized rows so garbage reads stay in-bounds and finite.

typedef _Float16 f16;
typedef _Float16 f16x4 __attribute__((ext_vector_type(4)));
typedef _Float16 f16x8 __attribute__((ext_vector_type(8)));
typedef float f32x16 __attribute__((ext_vector_type(16)));

// ---------------- workspace layout ----------------
#define OFF_H4    0                        // [64][63][12] floats
#define OFF_ST    48384                    // feature-63 state, per-b stride 1760
#define ST_L0     0                        // L0 pos 57..60   (4*32)  [pos][ch]
#define ST_L1     128                      // L1 pos 49..56   (8*32)
#define ST_L2     384                      // L2 pos 33..48   (16*32)
#define ST_L3     896                      // L3 pos 1..27    (27*32)
#define ST_STRIDE 1760
#define OFF_H40   (48384 + 64*1760)        // [64]
#define OFF_WPK   161088                   // float offset; f16 region after

#define RPAD 36                            // f16 per activation row
#define NROW 100

// ---------------- weight repack: fragment-ready f16 ----------------
__global__ __launch_bounds__(256) void repack_w(const float* __restrict__ wmid,
                                                f16* __restrict__ wpk) {
  const int idx = blockIdx.x * 256 + threadIdx.x;   // 589824 total
  const int j = idx & 7, r1 = idx >> 3;
  const int lane = r1 & 63, r2 = r1 >> 6;
  const int h = r2 & 1, r3 = r2 >> 1;
  const int t = r3 % 3, r4 = r3 / 3;
  const int f = r4 & 63, m = r4 >> 6;
  const int co = lane & 31;
  const int ci = h * 16 + (lane >> 5) * 8 + j;
  wpk[idx] = (f16)wmid[m * 196608 + (f * 32 + co) * 96 + ci * 3 + t];
}

// ---------------- MFMA tile for one mid layer ----------------
__device__ __forceinline__ void mfma_tile(
    int m, const f16* IN, f16* OUT, int d, int base,
    const f16* __restrict__ wpk, int f, int lane, const float* sBias)
{
  const int lg = lane >> 5;
  const int col = base + (lane & 31);

  f16x8 afr[6];
  const f16* wb = wpk + (m * 64 + f) * 6 * 512 + lane * 8;
#pragma unroll
  for (int u = 0; u < 6; ++u)
    afr[u] = *(const f16x8*)(wb + u * 512);

  f32x16 acc;
#pragma unroll
  for (int r = 0; r < 16; ++r)
    acc[r] = sBias[(r & 3) + 8 * (r >> 2) + 4 * lg];

#pragma unroll
  for (int t = 0; t < 3; ++t) {
#pragma unroll
    for (int h = 0; h < 2; ++h) {
      const f16* bp = IN + (col + t * d) * RPAD + h * 16 + lg * 8;
      f16x4 lo = *(const f16x4*)bp;
      f16x4 hi = *(const f16x4*)(bp + 4);
      f16x8 b = __builtin_shufflevector(lo, hi, 0, 1, 2, 3, 4, 5, 6, 7);
      acc = __builtin_amdgcn_mfma_f32_32x32x16_f16(afr[t * 2 + h], b, acc, 0, 0, 0);
    }
  }

#pragma unroll
  for (int q = 0; q < 4; ++q) {
    const int co0 = q * 8 + 4 * lg;
    f16x4 w;
#pragma unroll
    for (int e = 0; e < 4; ++e)
      w[e] = (f16)fmaxf(acc[q * 4 + e], 0.f);
    *(f16x4*)(OUT + col * RPAD + co0) = w;
  }
}

// ---------------- kernel A: parallel precompute ----------------
__global__ __launch_bounds__(256) void tcn_pre(
    const float* __restrict__ x, const float* __restrict__ xfc,
    const float* __restrict__ w0, const float* __restrict__ b0,
    const float* __restrict__ bmid,
    const float* __restrict__ wlast, const float* __restrict__ blast,
    const f16* __restrict__ wpk, float* __restrict__ ws)
{
  const int blk = blockIdx.x;
  const int b = blk >> 6;
  const int f = blk & 63;
  const bool lastf = (f == 63);
  const int tid = threadIdx.x;
  const int lane = tid & 63;
  const int g = __builtin_amdgcn_readfirstlane(tid >> 6);

  __shared__ float sIn[80];
  __shared__ float sBias[3][32];
  __shared__ f16 actA[NROW * RPAD];
  __shared__ f16 actB[NROW * RPAD];

  // ---- stage: input series, biases, zero-pad rows ----
  for (int t = tid; t < 80; t += 256) {
    float v = 0.f;
    if (t < 63)                 v = x[(b * 63 + t) * 64 + f];
    else if (t < 74 && !lastf)  v = xfc[(b * 12 + (t - 63)) * 63 + f];
    sIn[t] = v;
  }
  if (tid < 96) sBias[tid >> 5][tid & 31] = bmid[(tid >> 5) * 2048 + f * 32 + (tid & 31)];
  for (int i = tid; i < (NROW - 72) * RPAD; i += 256) actA[72 * RPAD + i] = (f16)0.f;
  for (int i = tid; i < (NROW - 68) * RPAD; i += 256) actB[68 * RPAD + i] = (f16)0.f;
  __syncthreads();

  // ---- L0 (d=1, 1->32ch), pos 0..71, out -> actA[pos][co] ----
  {
    const float* wb  = w0 + (f * 32 + g * 8) * 3;
    const float* bbp = b0 + f * 32 + g * 8;
#pragma unroll
    for (int it = 0; it < 2; ++it) {
      const int p = lane + it * 64;
      if (p < 72) {
        const float i0 = sIn[p], i1 = sIn[p + 1], i2 = sIn[p + 2];
        f16x4 wv[2];
#pragma unroll
        for (int j = 0; j < 8; ++j) {
          float v = fmaf(wb[j * 3 + 0], i0,
                    fmaf(wb[j * 3 + 1], i1,
                    fmaf(wb[j * 3 + 2], i2, bbp[j])));
          wv[j >> 2][j & 3] = (f16)fmaxf(v, 0.f);
        }
        *(f16x4*)(actA + p * RPAD + g * 8)     = wv[0];
        *(f16x4*)(actA + p * RPAD + g * 8 + 4) = wv[1];
      }
    }
  }
  __syncthreads();

  float* st = ws + OFF_ST + b * ST_STRIDE;

  // ---- L1 (d=2), valid pos 0..67: tiles base 0,32,64 (waves 0..2) ----
  if (lastf) {  // L0 slice pos 57..60 -> [pos][ch] f32
    for (int t = tid; t < 128; t += 256)
      st[ST_L0 + t] = (float)actA[(57 + (t >> 5)) * RPAD + (t & 31)];
  }
  if (g < 3) mfma_tile(0, actA, actB, 2, g * 32, wpk, f, lane, sBias[0]);
  __syncthreads();

  // ---- L2 (d=4), valid pos 0..59: tiles base 0,32 ----
  if (lastf) {  // L1 slice pos 49..56
    for (int t = tid; t < 256; t += 256)
      st[ST_L1 + t] = (float)actB[(49 + (t >> 5)) * RPAD + (t & 31)];
  }
  if (g < 2) mfma_tile(1, actB, actA, 4, g * 32, wpk, f, lane, sBias[1]);
  __syncthreads();

  // ---- L3 (d=8), valid pos 0..43: tiles base 0,32 ----
  if (lastf) {  // L2 slice pos 33..48
    for (int t = tid; t < 512; t += 256)
      st[ST_L2 + t] = (float)actA[(33 + (t >> 5)) * RPAD + (t & 31)];
  }
  if (g < 2) mfma_tile(2, actA, actB, 8, g * 32, wpk, f, lane, sBias[2]);
  __syncthreads();

  // ---- L4 (d=16, 32->1, no relu), pos 0..11 ----
  if (lastf) {  // L3 slice pos 1..27
    for (int t = tid; t < 864; t += 256)
      st[ST_L3 + t] = (float)actB[(1 + (t >> 5)) * RPAD + (t & 31)];
  }
  if (tid < 12) {
    const int p = tid;
    float acc = blast[f];
    const float* wl = wlast + f * 96;
#pragma unroll
    for (int k = 0; k < 3; ++k) {
      const int row = p + 16 * k;
#pragma unroll
      for (int ci0 = 0; ci0 < 32; ci0 += 4) {
        f16x4 av = *(const f16x4*)(actB + row * RPAD + ci0);
#pragma unroll
        for (int e = 0; e < 4; ++e)
          acc = fmaf(wl[(ci0 + e) * 3 + k], (float)av[e], acc);
      }
    }
    if (!lastf)      ws[OFF_H4 + (b * 63 + f) * 12 + p] = acc;
    else if (p == 0) ws[OFF_H40 + b] = acc;
  }
}

// ---------------- kernel B: sequential feature-63 chain (unchanged) ----------------

__device__ __forceinline__ void seq_mid(
    const float* __restrict__ wmL, float bb,
    const float* __restrict__ AIN, int inBase,
    float* __restrict__ AOUT, int outBase,
    int q, int d, int c, int h)
{
  float acc = 0.f;
  const int cib = h * 16;
#pragma unroll
  for (int ci = 0; ci < 16; ++ci) {
#pragma unroll
    for (int k = 0; k < 3; ++k)
      acc = fmaf(wmL[((cib + ci) * 3 + k) * 33 + c],
                 AIN[(q + k * d - inBase) * 32 + (cib + ci)], acc);
  }
  acc += __shfl_down(acc, 32);
  if (h == 0) AOUT[(q - outBase) * 32 + c] = fmaxf(acc + bb, 0.f);
}

__global__ __launch_bounds__(64) void tcn_seq(
    const float* __restrict__ x, const float* __restrict__ xfc,
    const float* __restrict__ w0, const float* __restrict__ b0,
    const float* __restrict__ wmid, const float* __restrict__ bmid,
    const float* __restrict__ wlast, const float* __restrict__ blast,
    const float* __restrict__ linW, const float* __restrict__ linb,
    const float* __restrict__ ws, float* __restrict__ out)
{
  const int b = blockIdx.x;
  const int tid = threadIdx.x;
  const int c = tid & 31, h = tid >> 5;

  __shared__ float wm[3][96 * 33];
  __shared__ float wl[96];
  __shared__ float L0s[15 * 32];
  __shared__ float L1s[19 * 32];
  __shared__ float L2s[27 * 32];
  __shared__ float L3s[43 * 32];
  __shared__ float in63[74];
  __shared__ float pre[12];

  for (int m = 0; m < 3; ++m) {
    const float* src = wmid + m * (2048 * 96) + 2016 * 96;
    for (int o = tid * 4; o < 3072; o += 64 * 4) {
      const float4 v = *reinterpret_cast<const float4*>(src + o);
      const int co = o / 96, r = o % 96;
      wm[m][(r + 0) * 33 + co] = v.x;
      wm[m][(r + 1) * 33 + co] = v.y;
      wm[m][(r + 2) * 33 + co] = v.z;
      wm[m][(r + 3) * 33 + co] = v.w;
    }
  }
  for (int t = tid; t < 96; t += 64) wl[t] = wlast[63 * 96 + t];

  {
    const float* stp = ws + OFF_ST + b * ST_STRIDE;
    for (int t = tid; t < 4 * 32;  t += 64) L0s[t] = stp[ST_L0 + t];
    for (int t = tid; t < 8 * 32;  t += 64) L1s[t] = stp[ST_L1 + t];
    for (int t = tid; t < 16 * 32; t += 64) L2s[t] = stp[ST_L2 + t];
    for (int t = tid; t < 27 * 32; t += 64) L3s[t] = stp[ST_L3 + t];
  }
  for (int t = tid; t < 63; t += 64) in63[t] = x[(b * 63 + t) * 64 + 63];

  const float lw  = (tid < 63) ? linW[tid] : 0.f;
  const float lwx = (tid < 63) ? linW[64 + tid] : 0.f;
  const float linb0 = linb[0];
  const float lw63  = linW[63];
  for (int i = 0; i < 12; ++i) {
    float v = 0.f;
    if (tid < 63)
      v = lw * ws[OFF_H4 + (b * 63 + tid) * 12 + i] + lwx * xfc[(b * 12 + i) * 63 + tid];
#pragma unroll
    for (int s = 32; s > 0; s >>= 1) v += __shfl_down(v, s);
    if (tid == 0) pre[i] = v + linb0;
  }

  const float w00 = w0[(2016 + c) * 3 + 0];
  const float w01 = w0[(2016 + c) * 3 + 1];
  const float w02 = w0[(2016 + c) * 3 + 2];
  const float b00 = b0[2016 + c];
  const float bm0 = bmid[0 * 2048 + 2016 + c];
  const float bm1 = bmid[1 * 2048 + 2016 + c];
  const float bm2 = bmid[2 * 2048 + 2016 + c];
  const float bl  = blast[63];
  __syncthreads();

  if (tid == 0) {
    const float o0 = pre[0] + lw63 * ws[OFF_H40 + b];
    out[b * 12 + 0] = o0;
    in63[63] = o0;
  }
  __syncthreads();

  for (int i = 1; i < 12; ++i) {
    if (h == 0) {
      const int q0 = 60 + i;
      float v = fmaf(w00, in63[q0], fmaf(w01, in63[q0 + 1], fmaf(w02, in63[q0 + 2], b00)));
      L0s[(q0 - 57) * 32 + c] = fmaxf(v, 0.f);
    }
    __syncthreads();
    seq_mid(wm[0], bm0, L0s, 57, L1s, 49, 56 + i, 2, c, h);
    __syncthreads();
    seq_mid(wm[1], bm1, L1s, 49, L2s, 33, 48 + i, 4, c, h);
    __syncthreads();
    seq_mid(wm[2], bm2, L2s, 33, L3s, 1,  32 + i, 8, c, h);
    __syncthreads();
    float acc = 0.f;
    if (tid < 32) {
#pragma unroll
      for (int k = 0; k < 3; ++k)
        acc = fmaf(wl[tid * 3 + k], L3s[(i + 16 * k - 1) * 32 + tid], acc);
    }
#pragma unroll
    for (int s = 16; s > 0; s >>= 1) acc += __shfl_down(acc, s);
    if (tid == 0) {
      const float h4v = acc + bl;
      const float oi = pre[i] + lw63 * h4v;
      out[b * 12 + i] = oi;
      if (i <= 10) in63[63 + i] = oi;
    }
    __syncthreads();
  }
}

// ---------------- launcher ----------------

extern "C" void kernel_launch(void* const* d_in, const int* in_sizes, int n_in,
                              void* d_out, int out_size, void* d_ws, size_t ws_size,
                              hipStream_t stream) {
  const float* x     = (const float*)d_in[0];
  const float* xfc   = (const float*)d_in[1];
  const float* w0    = (const float*)d_in[2];
  const float* b0    = (const float*)d_in[3];
  const float* wmid  = (const float*)d_in[4];
  const float* bmid  = (const float*)d_in[5];
  const float* wlast = (const float*)d_in[6];
  const float* blast = (const float*)d_in[7];
  const float* linW  = (const float*)d_in[8];
  const float* linb  = (const float*)d_in[9];
  float* out = (float*)d_out;
  float* ws  = (float*)d_ws;
  f16* wpk = (f16*)(ws + OFF_WPK);

  repack_w<<<2304, 256, 0, stream>>>(wmid, wpk);
  tcn_pre<<<64 * 64, 256, 0, stream>>>(x, xfc, w0, b0, bmid, wlast, blast, wpk, ws);
  tcn_seq<<<64, 64, 0, stream>>>(x, xfc, w0, b0, wmid, bmid, wlast, blast, linW, linb, ws, out);
}

// Round 4
// 49.556 us; speedup vs baseline: 6.5772x; 1.2412x over previous
//
#include <hip/hip_runtime.h>

// B=64, S=63, F=64, T=12, NF=63, OUT=1, C=32, K=3, DILS=(1,2,4,8,16)
//
// tcn_pre: mid layers on MFMA (f16 in, f32 accum) - unchanged from R2.
// tcn_seq this round: latency-optimized 1-wave chain:
//  - mid weights in VGPRs (144/lane), activations via uniform ds_read_b128
//    broadcasts, out_i carried in registers via shfl_xor full-wave reduce,
//    pre[] computed with one 6-round xor-tree over 12 simultaneous dots.

typedef _Float16 f16;
typedef _Float16 f16x4 __attribute__((ext_vector_type(4)));
typedef _Float16 f16x8 __attribute__((ext_vector_type(8)));
typedef float f32x16 __attribute__((ext_vector_type(16)));

// ---------------- workspace layout ----------------
#define OFF_H4    0                        // [64][63][12] floats
#define OFF_ST    48384                    // feature-63 state, per-b stride 1760
#define ST_L0     0                        // L0 pos 57..60   (4*32)  [pos][ch]
#define ST_L1     128                      // L1 pos 49..56   (8*32)
#define ST_L2     384                      // L2 pos 33..48   (16*32)
#define ST_L3     896                      // L3 pos 1..27    (27*32)
#define ST_STRIDE 1760
#define OFF_H40   (48384 + 64*1760)        // [64]
#define OFF_WPK   161088                   // float offset; f16 region after

#define RPAD 36
#define NROW 100

// ---------------- weight repack: fragment-ready f16 ----------------
__global__ __launch_bounds__(256) void repack_w(const float* __restrict__ wmid,
                                                f16* __restrict__ wpk) {
  const int idx = blockIdx.x * 256 + threadIdx.x;   // 589824 total
  const int j = idx & 7, r1 = idx >> 3;
  const int lane = r1 & 63, r2 = r1 >> 6;
  const int h = r2 & 1, r3 = r2 >> 1;
  const int t = r3 % 3, r4 = r3 / 3;
  const int f = r4 & 63, m = r4 >> 6;
  const int co = lane & 31;
  const int ci = h * 16 + (lane >> 5) * 8 + j;
  wpk[idx] = (f16)wmid[m * 196608 + (f * 32 + co) * 96 + ci * 3 + t];
}

// ---------------- MFMA tile for one mid layer ----------------
__device__ __forceinline__ void mfma_tile(
    int m, const f16* IN, f16* OUT, int d, int base,
    const f16* __restrict__ wpk, int f, int lane, const float* sBias)
{
  const int lg = lane >> 5;
  const int col = base + (lane & 31);

  f16x8 afr[6];
  const f16* wb = wpk + (m * 64 + f) * 6 * 512 + lane * 8;
#pragma unroll
  for (int u = 0; u < 6; ++u)
    afr[u] = *(const f16x8*)(wb + u * 512);

  f32x16 acc;
#pragma unroll
  for (int r = 0; r < 16; ++r)
    acc[r] = sBias[(r & 3) + 8 * (r >> 2) + 4 * lg];

#pragma unroll
  for (int t = 0; t < 3; ++t) {
#pragma unroll
    for (int h = 0; h < 2; ++h) {
      const f16* bp = IN + (col + t * d) * RPAD + h * 16 + lg * 8;
      f16x4 lo = *(const f16x4*)bp;
      f16x4 hi = *(const f16x4*)(bp + 4);
      f16x8 b = __builtin_shufflevector(lo, hi, 0, 1, 2, 3, 4, 5, 6, 7);
      acc = __builtin_amdgcn_mfma_f32_32x32x16_f16(afr[t * 2 + h], b, acc, 0, 0, 0);
    }
  }

#pragma unroll
  for (int q = 0; q < 4; ++q) {
    const int co0 = q * 8 + 4 * lg;
    f16x4 w;
#pragma unroll
    for (int e = 0; e < 4; ++e)
      w[e] = (f16)fmaxf(acc[q * 4 + e], 0.f);
    *(f16x4*)(OUT + col * RPAD + co0) = w;
  }
}

// ---------------- kernel A: parallel precompute ----------------
__global__ __launch_bounds__(256) void tcn_pre(
    const float* __restrict__ x, const float* __restrict__ xfc,
    const float* __restrict__ w0, const float* __restrict__ b0,
    const float* __restrict__ bmid,
    const float* __restrict__ wlast, const float* __restrict__ blast,
    const f16* __restrict__ wpk, float* __restrict__ ws)
{
  const int blk = blockIdx.x;
  const int b = blk >> 6;
  const int f = blk & 63;
  const bool lastf = (f == 63);
  const int tid = threadIdx.x;
  const int lane = tid & 63;
  const int g = __builtin_amdgcn_readfirstlane(tid >> 6);

  __shared__ float sIn[80];
  __shared__ float sBias[3][32];
  __shared__ f16 actA[NROW * RPAD];
  __shared__ f16 actB[NROW * RPAD];

  for (int t = tid; t < 80; t += 256) {
    float v = 0.f;
    if (t < 63)                 v = x[(b * 63 + t) * 64 + f];
    else if (t < 74 && !lastf)  v = xfc[(b * 12 + (t - 63)) * 63 + f];
    sIn[t] = v;
  }
  if (tid < 96) sBias[tid >> 5][tid & 31] = bmid[(tid >> 5) * 2048 + f * 32 + (tid & 31)];
  for (int i = tid; i < (NROW - 72) * RPAD; i += 256) actA[72 * RPAD + i] = (f16)0.f;
  for (int i = tid; i < (NROW - 68) * RPAD; i += 256) actB[68 * RPAD + i] = (f16)0.f;
  __syncthreads();

  // ---- L0 (d=1, 1->32ch), pos 0..71 ----
  {
    const float* wb  = w0 + (f * 32 + g * 8) * 3;
    const float* bbp = b0 + f * 32 + g * 8;
#pragma unroll
    for (int it = 0; it < 2; ++it) {
      const int p = lane + it * 64;
      if (p < 72) {
        const float i0 = sIn[p], i1 = sIn[p + 1], i2 = sIn[p + 2];
        f16x4 wv[2];
#pragma unroll
        for (int j = 0; j < 8; ++j) {
          float v = fmaf(wb[j * 3 + 0], i0,
                    fmaf(wb[j * 3 + 1], i1,
                    fmaf(wb[j * 3 + 2], i2, bbp[j])));
          wv[j >> 2][j & 3] = (f16)fmaxf(v, 0.f);
        }
        *(f16x4*)(actA + p * RPAD + g * 8)     = wv[0];
        *(f16x4*)(actA + p * RPAD + g * 8 + 4) = wv[1];
      }
    }
  }
  __syncthreads();

  float* st = ws + OFF_ST + b * ST_STRIDE;

  // ---- L1 (d=2) ----
  if (lastf) {
    for (int t = tid; t < 128; t += 256)
      st[ST_L0 + t] = (float)actA[(57 + (t >> 5)) * RPAD + (t & 31)];
  }
  if (g < 3) mfma_tile(0, actA, actB, 2, g * 32, wpk, f, lane, sBias[0]);
  __syncthreads();

  // ---- L2 (d=4) ----
  if (lastf) {
    for (int t = tid; t < 256; t += 256)
      st[ST_L1 + t] = (float)actB[(49 + (t >> 5)) * RPAD + (t & 31)];
  }
  if (g < 2) mfma_tile(1, actB, actA, 4, g * 32, wpk, f, lane, sBias[1]);
  __syncthreads();

  // ---- L3 (d=8) ----
  if (lastf) {
    for (int t = tid; t < 512; t += 256)
      st[ST_L2 + t] = (float)actA[(33 + (t >> 5)) * RPAD + (t & 31)];
  }
  if (g < 2) mfma_tile(2, actA, actB, 8, g * 32, wpk, f, lane, sBias[2]);
  __syncthreads();

  // ---- L4 (d=16, 32->1, no relu) ----
  if (lastf) {
    for (int t = tid; t < 864; t += 256)
      st[ST_L3 + t] = (float)actB[(1 + (t >> 5)) * RPAD + (t & 31)];
  }
  if (tid < 12) {
    const int p = tid;
    float acc = blast[f];
    const float* wl = wlast + f * 96;
#pragma unroll
    for (int k = 0; k < 3; ++k) {
      const int row = p + 16 * k;
#pragma unroll
      for (int ci0 = 0; ci0 < 32; ci0 += 4) {
        f16x4 av = *(const f16x4*)(actB + row * RPAD + ci0);
#pragma unroll
        for (int e = 0; e < 4; ++e)
          acc = fmaf(wl[(ci0 + e) * 3 + k], (float)av[e], acc);
      }
    }
    if (!lastf)      ws[OFF_H4 + (b * 63 + f) * 12 + p] = acc;
    else if (p == 0) ws[OFF_H40 + b] = acc;
  }
}

// ---------------- kernel B: sequential feature-63 chain ----------------
// One wave per batch. Weights in VGPRs; activations in LDS [pos][32] read as
// uniform-address float4 broadcasts; outputs carried in registers.

#define MID(WR, BB, SIN, SOUT, I0, DD, OI) do {                                 \
    float a0 = 0.f, a1 = 0.f, a2 = 0.f, a3 = 0.f;                               \
    _Pragma("unroll")                                                           \
    for (int k = 0; k < 3; ++k) {                                               \
      const float4* bp =                                                        \
          reinterpret_cast<const float4*>((SIN) + ((I0) + k * (DD)) * 32 + cib);\
      const float4 v0 = bp[0], v1 = bp[1], v2 = bp[2], v3 = bp[3];              \
      a0 = fmaf((WR)[0 + k],  v0.x, a0); a0 = fmaf((WR)[3 + k],  v0.y, a0);     \
      a0 = fmaf((WR)[6 + k],  v0.z, a0); a0 = fmaf((WR)[9 + k],  v0.w, a0);     \
      a1 = fmaf((WR)[12 + k], v1.x, a1); a1 = fmaf((WR)[15 + k], v1.y, a1);     \
      a1 = fmaf((WR)[18 + k], v1.z, a1); a1 = fmaf((WR)[21 + k], v1.w, a1);     \
      a2 = fmaf((WR)[24 + k], v2.x, a2); a2 = fmaf((WR)[27 + k], v2.y, a2);     \
      a2 = fmaf((WR)[30 + k], v2.z, a2); a2 = fmaf((WR)[33 + k], v2.w, a2);     \
      a3 = fmaf((WR)[36 + k], v3.x, a3); a3 = fmaf((WR)[39 + k], v3.y, a3);     \
      a3 = fmaf((WR)[42 + k], v3.z, a3); a3 = fmaf((WR)[45 + k], v3.w, a3);     \
    }                                                                           \
    float s2 = (a0 + a1) + (a2 + a3);                                           \
    s2 += __shfl_xor(s2, 32);                                                   \
    s2 = fmaxf(s2 + (BB), 0.f);                                                 \
    if (h == 0) (SOUT)[(OI) * 32 + c] = s2;                                     \
  } while (0)

__global__ __launch_bounds__(64, 1) void tcn_seq(
    const float* __restrict__ x, const float* __restrict__ xfc,
    const float* __restrict__ w0, const float* __restrict__ b0,
    const float* __restrict__ wmid, const float* __restrict__ bmid,
    const float* __restrict__ wlast, const float* __restrict__ blast,
    const float* __restrict__ linW, const float* __restrict__ linb,
    const float* __restrict__ ws, float* __restrict__ out)
{
  const int b = blockIdx.x;
  const int tid = threadIdx.x;
  const int c = tid & 31;
  const int h = tid >> 5;
  const int cib = h * 16;

  __shared__ __align__(16) float L0s[15 * 32];   // pos 57..71  (idx p-57)
  __shared__ __align__(16) float L1s[19 * 32];   // pos 49..67  (idx p-49)
  __shared__ __align__(16) float L2s[27 * 32];   // pos 33..59  (idx p-33)
  __shared__ __align__(16) float L3s[43 * 32];   // pos 1..43   (idx p-1)

  // ---- per-lane mid weights into registers (source-linear: wr[lci*3+k]) ----
  float wr0[48], wr1[48], wr2[48];
  {
    const float* base = wmid + (2016 + c) * 96 + cib * 3;
#pragma unroll
    for (int t = 0; t < 12; ++t) {
      const float4 v = *reinterpret_cast<const float4*>(base + t * 4);
      wr0[t * 4 + 0] = v.x; wr0[t * 4 + 1] = v.y;
      wr0[t * 4 + 2] = v.z; wr0[t * 4 + 3] = v.w;
    }
#pragma unroll
    for (int t = 0; t < 12; ++t) {
      const float4 v = *reinterpret_cast<const float4*>(base + 196608 + t * 4);
      wr1[t * 4 + 0] = v.x; wr1[t * 4 + 1] = v.y;
      wr1[t * 4 + 2] = v.z; wr1[t * 4 + 3] = v.w;
    }
#pragma unroll
    for (int t = 0; t < 12; ++t) {
      const float4 v = *reinterpret_cast<const float4*>(base + 2 * 196608 + t * 4);
      wr2[t * 4 + 0] = v.x; wr2[t * 4 + 1] = v.y;
      wr2[t * 4 + 2] = v.z; wr2[t * 4 + 3] = v.w;
    }
  }

  // ---- stage precomputed feature-63 state into LDS ----
  {
    const float* stp = ws + OFF_ST + b * ST_STRIDE;
    for (int t = tid; t < 128; t += 64) L0s[t] = stp[ST_L0 + t];
    for (int t = tid; t < 256; t += 64) L1s[t] = stp[ST_L1 + t];
    for (int t = tid; t < 512; t += 64) L2s[t] = stp[ST_L2 + t];
    for (int t = tid; t < 864; t += 64) L3s[t] = stp[ST_L3 + t];
  }

  // ---- scalar params ----
  const float w00 = w0[(2016 + c) * 3 + 0];
  const float w01 = w0[(2016 + c) * 3 + 1];
  const float w02 = w0[(2016 + c) * 3 + 2];
  const float b00 = b0[2016 + c];
  const float bm0 = bmid[0 * 2048 + 2016 + c];
  const float bm1 = bmid[1 * 2048 + 2016 + c];
  const float bm2 = bmid[2 * 2048 + 2016 + c];
  const float wl0 = wlast[63 * 96 + c * 3 + 0];
  const float wl1 = wlast[63 * 96 + c * 3 + 1];
  const float wl2 = wlast[63 * 96 + c * 3 + 2];
  const float bl   = blast[63];
  const float lw63 = linW[63];
  const float lb0  = linb[0];
  const float xv61 = x[(b * 63 + 61) * 64 + 63];
  const float xv62 = x[(b * 63 + 62) * 64 + 63];
  const float h40v = ws[OFF_H40 + b];

  // ---- linear partials accv[i]: all terms except feature 63 ----
  float accv[12];
  {
    float lw = 0.f, lwx = 0.f;
    if (tid < 63) { lw = linW[tid]; lwx = linW[64 + tid]; }
    float h4v[12], xv[12];
#pragma unroll
    for (int i = 0; i < 12; ++i) { h4v[i] = 0.f; xv[i] = 0.f; }
    if (tid < 63) {
      const float* hp = ws + OFF_H4 + (b * 63 + tid) * 12;
#pragma unroll
      for (int t = 0; t < 3; ++t) {
        const float4 v = *reinterpret_cast<const float4*>(hp + t * 4);
        h4v[t * 4 + 0] = v.x; h4v[t * 4 + 1] = v.y;
        h4v[t * 4 + 2] = v.z; h4v[t * 4 + 3] = v.w;
      }
#pragma unroll
      for (int i = 0; i < 12; ++i) xv[i] = xfc[(b * 12 + i) * 63 + tid];
    }
#pragma unroll
    for (int i = 0; i < 12; ++i) accv[i] = fmaf(lw, h4v[i], lwx * xv[i]);
#pragma unroll
    for (int r = 1; r < 64; r <<= 1) {
#pragma unroll
      for (int i = 0; i < 12; ++i) accv[i] += __shfl_xor(accv[i], r);
    }
#pragma unroll
    for (int i = 0; i < 12; ++i) accv[i] += lb0;
  }

  __syncthreads();   // staging visible

  float outv[12];
  outv[0] = accv[0] + lw63 * h40v;
  if (tid == 0) out[b * 12 + 0] = outv[0];

#pragma unroll
  for (int s = 1; s < 12; ++s) {
    // L0 @ pos 60+s ; inputs in63[60+s..62+s] from regs
    const float i0 = (s == 1) ? xv61 : ((s == 2) ? xv62 : outv[s - 3]);
    const float i1 = (s == 1) ? xv62 : outv[s - 2];
    const float i2 = outv[s - 1];
    {
      float v = fmaf(w00, i0, fmaf(w01, i1, fmaf(w02, i2, b00)));
      if (h == 0) L0s[(3 + s) * 32 + c] = fmaxf(v, 0.f);
    }
    __syncthreads();
    MID(wr0, bm0, L0s, L1s, s - 1, 2, 7 + s);    // L1 @ 56+s
    __syncthreads();
    MID(wr1, bm1, L1s, L2s, s - 1, 4, 15 + s);   // L2 @ 48+s
    __syncthreads();
    MID(wr2, bm2, L2s, L3s, s - 1, 8, 31 + s);   // L3 @ 32+s
    __syncthreads();
    // L4 @ s (reads L3 pos s, 16+s, 32+s) + linear
    float l4 = 0.f;
    if (h == 0)
      l4 = fmaf(wl0, L3s[(s - 1) * 32 + c],
           fmaf(wl1, L3s[(s + 15) * 32 + c],
           fmaf(wl2, L3s[(s + 31) * 32 + c], 0.f)));
#pragma unroll
    for (int r = 1; r < 64; r <<= 1) l4 += __shfl_xor(l4, r);
    const float h4x = l4 + bl;
    outv[s] = accv[s] + lw63 * h4x;
    if (tid == 0) out[b * 12 + s] = outv[s];
  }
}

// ---------------- launcher ----------------

extern "C" void kernel_launch(void* const* d_in, const int* in_sizes, int n_in,
                              void* d_out, int out_size, void* d_ws, size_t ws_size,
                              hipStream_t stream) {
  const float* x     = (const float*)d_in[0];
  const float* xfc   = (const float*)d_in[1];
  const float* w0    = (const float*)d_in[2];
  const float* b0    = (const float*)d_in[3];
  const float* wmid  = (const float*)d_in[4];
  const float* bmid  = (const float*)d_in[5];
  const float* wlast = (const float*)d_in[6];
  const float* blast = (const float*)d_in[7];
  const float* linW  = (const float*)d_in[8];
  const float* linb  = (const float*)d_in[9];
  float* out = (float*)d_out;
  float* ws  = (float*)d_ws;
  f16* wpk = (f16*)(ws + OFF_WPK);

  repack_w<<<2304, 256, 0, stream>>>(wmid, wpk);
  tcn_pre<<<64 * 64, 256, 0, stream>>>(x, xfc, w0, b0, bmid, wlast, blast, wpk, ws);
  tcn_seq<<<64, 64, 0, stream>>>(x, xfc, w0, b0, wmid, bmid, wlast, blast, linW, linb, ws, out);
}